// Round 2
// 79.455 us; speedup vs baseline: 1.0191x; 1.0191x over previous
//
#include <hip/hip_runtime.h>

// Fused single-kernel: 1x1-conv channel reduce + bilinear x4 (align_corners)
// + bias + ReLU. The channel reduction commutes with bilinear interpolation,
// so each block computes a small reduced-image tile z in LDS, then upsamples.
//
// Round-1 fix: phase-2 store was missing the ow0 column offset (every block
// wrote columns 0..127 -> 9/10 of output stayed memset-zero, absmax 4.5).
//
// x: (4,64,96,320) f32 | weight: (1,64,1,1) | bias: (1,) | out: (4,1,384,1280)

constexpr int C = 64, H = 96, W = 320, HW = H * W;
constexpr int Ho = 384, Wo = 1280;
constexpr int TOH = 16, TOW = 128;          // output tile per block
constexpr int NTR = Ho / TOH;               // 24
constexpr int NTC = Wo / TOW;               // 10
constexpr int NWG = 4 * NTR * NTC;          // 960 blocks (=8*120, XCD-bijective)
constexpr int ZR = 6, ZC = 40;              // staged reduced tile (rows span <=6,
                                            // cols span <=37, padded to 40)

__global__ __launch_bounds__(256)
void fused_kernel(const float* __restrict__ x,
                  const float* __restrict__ wgt,
                  const float* __restrict__ bias,
                  float* __restrict__ out)
{
    constexpr float RH = 95.0f / 383.0f;    // (H-1)/(Ho-1), f32 as in JAX
    constexpr float RW = 319.0f / 1279.0f;  // (W-1)/(Wo-1)

    __shared__ float ws[C];
    __shared__ float zt[ZR][ZC];

    // XCD-aware swizzle (960 % 8 == 0 -> bijective): each XCD gets a
    // contiguous 120-tile chunk so shared input rows stay in its private L2.
    int bid = blockIdx.x;
    bid = (bid & 7) * (NWG / 8) + (bid >> 3);

    const int tc = bid % NTC;
    const int t2 = bid / NTC;
    const int tr = t2 % NTR;
    const int b  = t2 / NTR;

    const int tid = threadIdx.x;
    if (tid < C) ws[tid] = wgt[tid];
    __syncthreads();

    const int oh0  = tr * TOH;
    const int ow0  = tc * TOW;
    const int r_lo = min((int)((float)oh0 * RH), H - 2);  // first input row
    const int j_lo = min((int)((float)ow0 * RW), W - 2);  // first input col
    const int jb   = j_lo & ~3;                           // float4-aligned base

    // ---- phase 1: z[r][j] = sum_c w[c]*x[b,c,r_lo+r,jb+j] into LDS.
    // 60 groups of 4 lanes; each lane accumulates 16 channels of one float4,
    // then a 2-step xor-shuffle folds the 4 channel-subsets.
    {
        const int g  = tid >> 2;
        const int lc = tid & 3;
        if (g < ZR * (ZC / 4)) {
            const int r  = g / (ZC / 4);
            const int jq = g - r * (ZC / 4);
            const int rr = min(r_lo + r, H - 1);      // clamped dup rows unread
            const int cj = min(jb + 4 * jq, W - 4);   // clamped dup cols unread
            const float* p = x + (size_t)b * C * HW + (size_t)rr * W + cj;
            float4 acc = make_float4(0.f, 0.f, 0.f, 0.f);
            #pragma unroll
            for (int k = 0; k < 16; ++k) {
                const int ch = lc * 16 + k;
                const float4 v = *(const float4*)(p + (size_t)ch * HW);
                const float wv = ws[ch];
                acc.x += v.x * wv; acc.y += v.y * wv;
                acc.z += v.z * wv; acc.w += v.w * wv;
            }
            acc.x += __shfl_xor(acc.x, 1); acc.y += __shfl_xor(acc.y, 1);
            acc.z += __shfl_xor(acc.z, 1); acc.w += __shfl_xor(acc.w, 1);
            acc.x += __shfl_xor(acc.x, 2); acc.y += __shfl_xor(acc.y, 2);
            acc.z += __shfl_xor(acc.z, 2); acc.w += __shfl_xor(acc.w, 2);
            if (lc == 0) *(float4*)&zt[r][4 * jq] = acc;
        }
    }
    __syncthreads();

    // ---- phase 2: upsample 16 rows x 32 float4 from LDS.
    // Half-wave (32 lanes) covers one full tile row -> 512 B store segments.
    const float bv   = bias[0];
    const int   fq   = tid & 31;       // float4 index within tile row
    const int   rb   = tid >> 5;       // 0..7
    #pragma unroll
    for (int u = 0; u < 2; ++u) {
        const int   row = rb + 8 * u;
        const int   oh  = oh0 + row;
        const float phh = (float)oh * RH;
        const int   i0  = min((int)phh, H - 2);
        const float wy  = phh - (float)i0;
        const float* za = zt[i0 - r_lo];
        const float* zb = zt[i0 - r_lo + 1];
        float vals[4];
        #pragma unroll
        for (int j = 0; j < 4; ++j) {
            const int   ow = ow0 + 4 * fq + j;
            const float pw = (float)ow * RW;
            const int   j0 = min((int)pw, W - 2);
            const float wx = pw - (float)j0;
            const int   L  = j0 - jb;                 // 0..35, fits ZC=40
            const float top = za[L] * (1.f - wx) + za[L + 1] * wx;
            const float bot = zb[L] * (1.f - wx) + zb[L + 1] * wx;
            const float v   = top * (1.f - wy) + bot * wy + bv;
            vals[j] = fmaxf(v, 0.f);
        }
        ((float4*)(out + ((size_t)b * Ho + oh) * Wo + ow0))[fq]
            = make_float4(vals[0], vals[1], vals[2], vals[3]);
    }
}

extern "C" void kernel_launch(void* const* d_in, const int* in_sizes, int n_in,
                              void* d_out, int out_size, void* d_ws, size_t ws_size,
                              hipStream_t stream) {
    fused_kernel<<<dim3(NWG), 256, 0, stream>>>(
        (const float*)d_in[0], (const float*)d_in[1],
        (const float*)d_in[2], (float*)d_out);
}